// Round 2
// baseline (538.752 us; speedup 1.0000x reference)
//
#include <hip/hip_runtime.h>

#define BATCH 16
#define CIN 512
#define COUT 512
#define RES 64
#define K_TILES 72   // 9 taps * 512 cin / BK=64

typedef __attribute__((ext_vector_type(8))) short bf16x8;
typedef __attribute__((ext_vector_type(4))) float f32x4;

// zero-initialized device global: boundary-tap source for global_load_lds.
__device__ __align__(16) unsigned short g_zero[64];

static __device__ __forceinline__ unsigned short f2bf(float f) {
    unsigned int u = __float_as_uint(f);
    u += 0x7fffu + ((u >> 16) & 1u);   // round-to-nearest-even
    return (unsigned short)(u >> 16);
}

static __device__ __forceinline__ void gload16(const void* g, void* l) {
    __builtin_amdgcn_global_load_lds(
        (const __attribute__((address_space(1))) void*)g,
        (__attribute__((address_space(3))) void*)l, 16, 0, 0);
}

// ---- fused prep1: blocks [0,2048): styles[b][i] ; blocks [2048,2560): wA + wsq ----
__global__ void k_prep1(const float* __restrict__ w, const float* __restrict__ aw,
                        const float* __restrict__ ab, const float* __restrict__ weight,
                        float* __restrict__ styles, unsigned short* __restrict__ wA,
                        float* __restrict__ wsq) {
    if (blockIdx.x < 2048) {
        int wid  = (blockIdx.x * blockDim.x + threadIdx.x) >> 6;
        int lane = threadIdx.x & 63;
        int b = wid >> 9, i = wid & 511;
        const float* wrow = w + b * 512;
        const float* arow = aw + (size_t)i * 512;
        float acc = 0.f;
        for (int k = lane; k < 512; k += 64) acc += wrow[k] * arow[k];
        for (int off = 32; off; off >>= 1) acc += __shfl_down(acc, off, 64);
        if (lane == 0) styles[wid] = acc * 0.04419417382415922f + ab[i];
    } else {
        int o = blockIdx.x - 2048;
        __shared__ float lw[4608];
        for (int idx = threadIdx.x; idx < 4608; idx += 256)
            lw[idx] = weight[(size_t)o * 4608 + idx];
        __syncthreads();
        int i = threadIdx.x * 2;
        float sq0 = 0.f, sq1 = 0.f;
#pragma unroll
        for (int t = 0; t < 9; ++t) {
            float v0 = lw[i * 9 + t], v1 = lw[(i + 1) * 9 + t];
            sq0 += v0 * v0; sq1 += v1 * v1;
            unsigned* dst = (unsigned*)(wA + (((size_t)t * COUT + o) << 9));
            dst[threadIdx.x] = (unsigned)f2bf(v0) | ((unsigned)f2bf(v1) << 16);
        }
        *(float2*)(wsq + ((size_t)o << 9) + i) = make_float2(sq0, sq1);
    }
}

// ---- dcoefs[b][o] = rsqrt(sum_i styles^2 * wsq[o,i] + 1e-8) ----
__global__ void k_dcoefs(const float* __restrict__ wsq, const float* __restrict__ styles,
                         float* __restrict__ dcoefs) {
    int wid  = (blockIdx.x * blockDim.x + threadIdx.x) >> 6;
    int lane = threadIdx.x & 63;
    int b = wid >> 9, o = wid & 511;
    const float* srow = styles + b * 512;
    const float* qrow = wsq + ((size_t)o << 9);
    float acc = 0.f;
    for (int i = lane; i < 512; i += 64) {
        float s = srow[i];
        acc += s * s * qrow[i];
    }
    for (int off = 32; off; off >>= 1) acc += __shfl_down(acc, off, 64);
    if (lane == 0) dcoefs[wid] = rsqrtf(acc + 1e-8f);
}

// ---- xt[b][h][w][i] = bf16(x[b][i][h][w] * styles[b][i])  (CHW->HWC + style fold) ----
// One block per (b,h): full 512-channel transpose in LDS, so each thread writes a
// contiguous 16B x8 = 128B channel-run and each 1KB output row is fully covered.
__global__ __launch_bounds__(512) void k_xpose(const float* __restrict__ x,
                                               const float* __restrict__ styles,
                                               unsigned short* __restrict__ xt) {
    int bh = blockIdx.x;          // b*64 + h
    int b = bh >> 6, h = bh & 63;
    __shared__ float tile[512][65];
    __shared__ float st[512];
    const int tid = threadIdx.x;
    st[tid] = styles[b * 512 + tid];
    __syncthreads();
    const float* src = x + ((size_t)b * 512) * 4096 + h * 64;
#pragma unroll
    for (int it = 0; it < 16; ++it) {
        int idx = it * 512 + tid;               // 0..8191
        int c = idx >> 4, w4 = (idx & 15) * 4;
        float4 v = *(const float4*)(src + (size_t)c * 4096 + w4);
        float s = st[c];
        tile[c][w4] = v.x * s; tile[c][w4 + 1] = v.y * s;
        tile[c][w4 + 2] = v.z * s; tile[c][w4 + 3] = v.w * s;
    }
    __syncthreads();
    const int w = tid >> 3, l3 = tid & 7;
    unsigned short* outp = xt + (((size_t)bh * 64 + w) << 9) + l3 * 64;
#pragma unroll
    for (int g = 0; g < 8; ++g) {
        int bb = (g ^ l3) * 8;                  // XOR block order: 2-way banks (free)
        int c0 = l3 * 64 + bb;
        unsigned pk0 = (unsigned)f2bf(tile[c0 + 0][w]) | ((unsigned)f2bf(tile[c0 + 1][w]) << 16);
        unsigned pk1 = (unsigned)f2bf(tile[c0 + 2][w]) | ((unsigned)f2bf(tile[c0 + 3][w]) << 16);
        unsigned pk2 = (unsigned)f2bf(tile[c0 + 4][w]) | ((unsigned)f2bf(tile[c0 + 5][w]) << 16);
        unsigned pk3 = (unsigned)f2bf(tile[c0 + 6][w]) | ((unsigned)f2bf(tile[c0 + 7][w]) << 16);
        *(uint4*)(outp + bb) = make_uint4(pk0, pk1, pk2, pk3);
    }
}

// ---------------- main conv: implicit GEMM, 256x256 tile, free-running 4-phase ----
// 8 waves (2M x 4N), BK=64, linear LDS tiles (256 rows x 64 halfs, XOR-quad swizzle),
// reads issued one phase ahead (compiler inserts counted lgkm waits), stages bunched
// once per K-tile with counted vmcnt(8). Only TWO barriers per K-tile:
//   B2 = {lgkmcnt(0); barrier} before staging  (all reads of buf[cur] done block-wide)
//   B1 = {vmcnt(8);   barrier} after staging   (buf[nxt] fully landed block-wide)
__global__ __launch_bounds__(512, 2)
void k_conv(const unsigned short* __restrict__ wA, const unsigned short* __restrict__ xt,
            const float* __restrict__ dcoefs,
            const float* __restrict__ noise, const float* __restrict__ nstr,
            const float* __restrict__ bias, float* __restrict__ out) {
    __shared__ __align__(16) unsigned short lA[2][16384];   // [dbuf][256 rows * 64 halfs]
    __shared__ __align__(16) unsigned short lB[2][16384];
    __shared__ float sdc[256];
    __shared__ float sbias[256];

    const int tid  = threadIdx.x;
    const int lane = tid & 63;
    const int wave = tid >> 6;
    const int wm = wave >> 2;      // 0..1  (M waves: 128 o-rows each)
    const int wn = wave & 3;       // 0..3  (N waves: 64 pixels each)

    // XCD-aware bijective swizzle (512 = 8*64): o-block fastest so the two blocks
    // sharing a B-tile are consecutive within an XCD.
    const int orig  = blockIdx.x;
    const int wgid  = (orig & 7) * 64 + (orig >> 3);
    const int o_blk = wgid & 1;
    const int ptile = wgid >> 1;           // 0..255
    const int b     = ptile >> 4;          // batch
    const int h0    = (ptile & 15) << 2;   // 4 image rows per 256-pixel tile
    const int o0    = o_blk * 256;
    const int p0    = (ptile & 15) << 8;   // pixel base

    // staging constants: thread covers row srow (of 64) at phys quad tid&7
    const int srow  = tid >> 3;                        // 0..63
    const int qsrc8 = ((tid & 7) ^ (srow & 7)) * 8;    // inverse-swizzled source quad (halfs)

    // fragment-read constants (bytes)
    const int l7 = lane & 7;
    const int a_off = (wm * 128 + (lane & 15)) * 128;
    const int b_off = (wn * 64  + (lane & 15)) * 128;
    const int qk0 = (((lane >> 4)    ) ^ l7) * 16;     // ks=0: q_log = lane>>4
    const int qk1 = (((lane >> 4) | 4) ^ l7) * 16;     // ks=1: q_log = 4 + lane>>4

    // ---- incremental stage-pointer streams (recomputed once per tap) ----
    const unsigned short* pA;
    const unsigned short* pB[4];
    int aB[4];

    auto recompA = [&](int ktt) {
        pA = wA + (((size_t)((ktt >> 3) * COUT + o0 + srow)) << 9)
                + ((ktt & 7) << 6) + qsrc8;
    };
    auto recompB = [&](int ktt) {
        int tap = ktt >> 3;
        int ty = tap / 3;
        int dy = ty - 1, dx = tap - ty * 3 - 1;
        int wv = srow + dx;
        bool wok = (unsigned)wv < 64u;
        int i0 = (ktt & 7) << 6;
#pragma unroll
        for (int s = 0; s < 4; ++s) {
            int hh = h0 + s + dy;
            bool ok = wok && ((unsigned)hh < 64u);
            pB[s] = ok ? xt + (((size_t)(b * 4096 + hh * 64 + wv)) << 9) + i0 + qsrc8
                       : g_zero + qsrc8;
            aB[s] = ok ? 64 : 0;
        }
    };
    auto stageA = [&](int d) {
        char* lb = (char*)&lA[d][0] + wave * 1024;
        gload16(pA,               lb);
        gload16(pA + (64  << 9),  lb + 8192);
        gload16(pA + (128 << 9),  lb + 16384);
        gload16(pA + (192 << 9),  lb + 24576);
    };
    auto stageB = [&](int d) {
        char* lb = (char*)&lB[d][0] + wave * 1024;
        gload16(pB[0], lb);
        gload16(pB[1], lb + 8192);
        gload16(pB[2], lb + 16384);
        gload16(pB[3], lb + 24576);
    };

    bf16x8 afr[2][4], bfr[2][4];
    f32x4 acc[8][4];
#pragma unroll
    for (int i = 0; i < 8; ++i)
#pragma unroll
        for (int j = 0; j < 4; ++j) acc[i][j] = (f32x4){0.f, 0.f, 0.f, 0.f};

#define RD_A(S, H, QK, BASE) do {                                            \
    afr[S][0] = *(const bf16x8*)((BASE) + a_off + ((H)*4 + 0)*2048 + (QK));  \
    afr[S][1] = *(const bf16x8*)((BASE) + a_off + ((H)*4 + 1)*2048 + (QK));  \
    afr[S][2] = *(const bf16x8*)((BASE) + a_off + ((H)*4 + 2)*2048 + (QK));  \
    afr[S][3] = *(const bf16x8*)((BASE) + a_off + ((H)*4 + 3)*2048 + (QK));  \
} while (0)
#define RD_B(S, QK, BASE) do {                                               \
    bfr[S][0] = *(const bf16x8*)((BASE) + b_off + 0*2048 + (QK));            \
    bfr[S][1] = *(const bf16x8*)((BASE) + b_off + 1*2048 + (QK));            \
    bfr[S][2] = *(const bf16x8*)((BASE) + b_off + 2*2048 + (QK));            \
    bfr[S][3] = *(const bf16x8*)((BASE) + b_off + 3*2048 + (QK));            \
} while (0)
#define MM(AS, BS, H) do {                                                   \
    _Pragma("unroll")                                                        \
    for (int _j = 0; _j < 4; ++_j) {                                         \
        _Pragma("unroll")                                                    \
        for (int _fn = 0; _fn < 4; ++_fn)                                    \
            acc[(H)*4 + _j][_fn] = __builtin_amdgcn_mfma_f32_16x16x32_bf16(  \
                afr[AS][_j], bfr[BS][_fn], acc[(H)*4 + _j][_fn], 0, 0, 0);   \
    }                                                                        \
} while (0)

    // ---- prologue: stage tiles 0 and 1; counted landing; initial ks0 reads ----
    recompA(0); recompB(0); stageA(0); stageB(0);
    recompA(1); recompB(1); stageA(1); stageB(1);
    recompA(2); recompB(2);                       // stream state for iter0 ph3 (ktt=2)
    asm volatile("s_waitcnt vmcnt(8)" ::: "memory");   // tile0 landed, tile1 in flight
    __builtin_amdgcn_s_barrier();
    {
        const char* bA0 = (const char*)&lA[0][0];
        const char* bB0 = (const char*)&lB[0][0];
        RD_A(0, 0, qk0, bA0);
        RD_B(0, qk0, bB0);
    }

    for (int kt = 0; kt < K_TILES; ++kt) {
        const int cur = kt & 1;
        const char* bA = (const char*)&lA[cur][0];
        const char* bB = (const char*)&lB[cur][0];
        const char* nA = (const char*)&lA[cur ^ 1][0];
        const char* nB = (const char*)&lB[cur ^ 1][0];

        // ph0: issue A(h1,ks0); MFMA h0 x ks0
        RD_A(1, 1, qk0, bA);
        __builtin_amdgcn_sched_barrier(0);
        __builtin_amdgcn_s_setprio(1);
        MM(0, 0, 0);
        __builtin_amdgcn_s_setprio(0);

        // ph1: issue A(h0,ks1) + B(ks1); MFMA h1 x ks0
        RD_A(0, 0, qk1, bA);
        RD_B(1, qk1, bB);
        __builtin_amdgcn_sched_barrier(0);
        __builtin_amdgcn_s_setprio(1);
        MM(1, 0, 1);
        __builtin_amdgcn_s_setprio(0);

        // ph2: issue A(h1,ks1); MFMA h0 x ks1; then drain reads + barrier (B2)
        RD_A(1, 1, qk1, bA);
        __builtin_amdgcn_sched_barrier(0);
        __builtin_amdgcn_s_setprio(1);
        MM(0, 1, 0);
        __builtin_amdgcn_s_setprio(0);
        asm volatile("s_waitcnt lgkmcnt(0)" ::: "memory");
        __builtin_amdgcn_s_barrier();                         // B2

        // ph3: stage kt+2 into buf[cur]; counted vmcnt; barrier (B1);
        //      issue next-tile ks0 reads; MFMA h1 x ks1
        if (kt + 2 < K_TILES) {
            stageA(cur); stageB(cur);
            int nk = kt + 3;
            if (nk < K_TILES) {
                if ((nk & 7) == 0) { recompA(nk); recompB(nk); }
                else {
                    pA += 64;
                    pB[0] += aB[0]; pB[1] += aB[1]; pB[2] += aB[2]; pB[3] += aB[3];
                }
            }
            asm volatile("s_waitcnt vmcnt(8)" ::: "memory");  // kt+1 fully landed
        } else {
            asm volatile("s_waitcnt vmcnt(0)" ::: "memory");  // tail drain
        }
        __builtin_amdgcn_s_barrier();                         // B1
        if (kt + 1 < K_TILES) {
            RD_A(0, 0, qk0, nA);
            RD_B(0, qk0, nB);
        }
        __builtin_amdgcn_sched_barrier(0);
        __builtin_amdgcn_s_setprio(1);
        MM(1, 1, 1);
        __builtin_amdgcn_s_setprio(0);
    }

    // ---- epilogue ----
    if (tid < 256) {
        sdc[tid]   = dcoefs[b * 512 + o0 + tid];
        sbias[tid] = bias[o0 + tid];
    }
    __syncthreads();
    const float ns = nstr[0];
    const int prow = (lane >> 4) * 4;
#pragma unroll
    for (int fm = 0; fm < 8; ++fm) {
        const int ob = wm * 128 + fm * 16 + prow;     // o - o0
#pragma unroll
        for (int fn = 0; fn < 4; ++fn) {
            const int p = p0 + wn * 64 + fn * 16 + (lane & 15);
            const float nv = noise[p] * ns;
#pragma unroll
            for (int rg = 0; rg < 4; ++rg) {
                const int oo = ob + rg;
                float v = acc[fm][fn][rg] * sdc[oo] + nv + sbias[oo];
                v = (v > 0.f ? v : 0.2f * v) * 1.41421356f;
                out[((size_t)(b * COUT + o0 + oo) << 12) + p] = v;
            }
        }
    }
#undef RD_A
#undef RD_B
#undef MM
}

// -------- fallback: fully self-contained fp32 conv (touches NO workspace) --------
__global__ void k_conv_naive(const float* __restrict__ x, const float* __restrict__ w,
                             const float* __restrict__ weight,
                             const float* __restrict__ aw, const float* __restrict__ ab,
                             const float* __restrict__ noise, const float* __restrict__ nstr,
                             const float* __restrict__ bias, float* __restrict__ out) {
    const int o = blockIdx.x, b = blockIdx.y;
    __shared__ float ss[512];
    __shared__ float red[256];
    const float* wv = w + b * 512;
    for (int i = threadIdx.x; i < 512; i += 256) {
        const float* arow = aw + (size_t)i * 512;
        float acc = 0.f;
        for (int k = 0; k < 512; ++k) acc += wv[k] * arow[k];
        ss[i] = acc * 0.04419417382415922f + ab[i];
    }
    __syncthreads();
    float part = 0.f;
    for (int i = threadIdx.x; i < 512; i += 256) {
        float s = ss[i], sq = 0.f;
#pragma unroll
        for (int k = 0; k < 9; ++k) { float v = weight[((size_t)o * 512 + i) * 9 + k]; sq += v * v; }
        part += s * s * sq;
    }
    red[threadIdx.x] = part;
    __syncthreads();
    for (int st = 128; st; st >>= 1) {
        if (threadIdx.x < st) red[threadIdx.x] += red[threadIdx.x + st];
        __syncthreads();
    }
    const float dcoef = rsqrtf(red[0] + 1e-8f);

    float acc[16];
#pragma unroll
    for (int j = 0; j < 16; ++j) acc[j] = 0.f;
    for (int i = 0; i < 512; ++i) {
        const float s = ss[i];
        float wk[9];
#pragma unroll
        for (int k = 0; k < 9; ++k) wk[k] = weight[((size_t)o * 512 + i) * 9 + k] * s;
        const float* xp = x + ((size_t)b * 512 + i) * 4096;
#pragma unroll
        for (int j = 0; j < 16; ++j) {
            const int p = (j << 8) + threadIdx.x;
            const int h = p >> 6, ww = p & 63;
            float a = acc[j];
#pragma unroll
            for (int ky = 0; ky < 3; ++ky) {
                int hh = h + ky - 1;
                if ((unsigned)hh < 64u) {
#pragma unroll
                    for (int kx = 0; kx < 3; ++kx) {
                        int wv2 = ww + kx - 1;
                        if ((unsigned)wv2 < 64u) a += wk[ky * 3 + kx] * xp[hh * 64 + wv2];
                    }
                }
            }
            acc[j] = a;
        }
    }
    const float ns = nstr[0], bs = bias[o];
#pragma unroll
    for (int j = 0; j < 16; ++j) {
        int p = (j << 8) + threadIdx.x;
        float v = acc[j] * dcoef + noise[p] * ns + bs;
        v = (v > 0.f ? v : 0.2f * v) * 1.41421356f;
        out[((size_t)(b * COUT + o) << 12) + p] = v;
    }
}

extern "C" void kernel_launch(void* const* d_in, const int* in_sizes, int n_in,
                              void* d_out, int out_size, void* d_ws, size_t ws_size,
                              hipStream_t stream) {
    const float* x   = (const float*)d_in[0];
    const float* w   = (const float*)d_in[1];
    const float* wt  = (const float*)d_in[2];
    const float* aw  = (const float*)d_in[3];
    const float* ab  = (const float*)d_in[4];
    const float* bs  = (const float*)d_in[5];
    const float* nc  = (const float*)d_in[6];
    const float* nst = (const float*)d_in[7];
    float* out = (float*)d_out;

    char* ws = (char*)d_ws;
    float* styles = (float*)ws;                                  // 32 KB
    float* dcoefs = (float*)(ws + 32 * 1024);                    // 32 KB
    float* wsq    = (float*)(ws + 64 * 1024);                    // 1 MB
    unsigned short* wA = (unsigned short*)(ws + (2 << 20));      // 4.7 MB
    unsigned short* xt = (unsigned short*)(ws + (2 << 20) + 4718592ull); // 67.1 MB
    const size_t need = (size_t)(2 << 20) + 4718592ull + 67108864ull;    // ~70.5 MB

    if (d_ws != nullptr && ws_size >= need) {
        k_prep1<<<2560, 256, 0, stream>>>(w, aw, ab, wt, styles, wA, wsq);
        k_dcoefs<<<2048, 256, 0, stream>>>(wsq, styles, dcoefs);
        k_xpose<<<1024, 512, 0, stream>>>(x, styles, xt);
        k_conv<<<512, 512, 0, stream>>>(wA, xt, dcoefs, nc, nst, bs, out);
    } else {
        k_conv_naive<<<dim3(512, 16), 256, 0, stream>>>(x, w, wt, aw, ab, nc, nst, bs, out);
    }
}

// Round 3
// 525.955 us; speedup vs baseline: 1.0243x; 1.0243x over previous
//
#include <hip/hip_runtime.h>

#define BATCH 16
#define CIN 512
#define COUT 512
#define RES 64
#define K_TILES 72   // 9 taps * 512 cin / BK=64

typedef __attribute__((ext_vector_type(8))) short bf16x8;
typedef __attribute__((ext_vector_type(4))) float f32x4;

// zero-initialized device global: boundary-tap source for global_load_lds.
__device__ __align__(16) unsigned short g_zero[64];

static __device__ __forceinline__ unsigned short f2bf(float f) {
    unsigned int u = __float_as_uint(f);
    u += 0x7fffu + ((u >> 16) & 1u);   // round-to-nearest-even
    return (unsigned short)(u >> 16);
}

static __device__ __forceinline__ void gload16(const void* g, void* l) {
    __builtin_amdgcn_global_load_lds(
        (const __attribute__((address_space(1))) void*)g,
        (__attribute__((address_space(3))) void*)l, 16, 0, 0);
}

// ---- fused prep1: blocks [0,2048): styles[b][i] ; blocks [2048,2560): wA + wsq ----
__global__ void k_prep1(const float* __restrict__ w, const float* __restrict__ aw,
                        const float* __restrict__ ab, const float* __restrict__ weight,
                        float* __restrict__ styles, unsigned short* __restrict__ wA,
                        float* __restrict__ wsq) {
    if (blockIdx.x < 2048) {
        int wid  = (blockIdx.x * blockDim.x + threadIdx.x) >> 6;
        int lane = threadIdx.x & 63;
        int b = wid >> 9, i = wid & 511;
        const float* wrow = w + b * 512;
        const float* arow = aw + (size_t)i * 512;
        float acc = 0.f;
        for (int k = lane; k < 512; k += 64) acc += wrow[k] * arow[k];
        for (int off = 32; off; off >>= 1) acc += __shfl_down(acc, off, 64);
        if (lane == 0) styles[wid] = acc * 0.04419417382415922f + ab[i];
    } else {
        int o = blockIdx.x - 2048;
        __shared__ float lw[4608];
        for (int idx = threadIdx.x; idx < 4608; idx += 256)
            lw[idx] = weight[(size_t)o * 4608 + idx];
        __syncthreads();
        int i = threadIdx.x * 2;
        float sq0 = 0.f, sq1 = 0.f;
#pragma unroll
        for (int t = 0; t < 9; ++t) {
            float v0 = lw[i * 9 + t], v1 = lw[(i + 1) * 9 + t];
            sq0 += v0 * v0; sq1 += v1 * v1;
            unsigned* dst = (unsigned*)(wA + (((size_t)t * COUT + o) << 9));
            dst[threadIdx.x] = (unsigned)f2bf(v0) | ((unsigned)f2bf(v1) << 16);
        }
        *(float2*)(wsq + ((size_t)o << 9) + i) = make_float2(sq0, sq1);
    }
}

// ---- dcoefs[b][o] = rsqrt(sum_i styles^2 * wsq[o,i] + 1e-8) ----
__global__ void k_dcoefs(const float* __restrict__ wsq, const float* __restrict__ styles,
                         float* __restrict__ dcoefs) {
    int wid  = (blockIdx.x * blockDim.x + threadIdx.x) >> 6;
    int lane = threadIdx.x & 63;
    int b = wid >> 9, o = wid & 511;
    const float* srow = styles + b * 512;
    const float* qrow = wsq + ((size_t)o << 9);
    float acc = 0.f;
    for (int i = lane; i < 512; i += 64) {
        float s = srow[i];
        acc += s * s * qrow[i];
    }
    for (int off = 32; off; off >>= 1) acc += __shfl_down(acc, off, 64);
    if (lane == 0) dcoefs[wid] = rsqrtf(acc + 1e-8f);
}

// ---- xt[b][h][w][i] = bf16(x[b][i][h][w] * styles[b][i])  (CHW->HWC + style fold) ----
__global__ __launch_bounds__(512) void k_xpose(const float* __restrict__ x,
                                               const float* __restrict__ styles,
                                               unsigned short* __restrict__ xt) {
    int bh = blockIdx.x;          // b*64 + h
    int b = bh >> 6, h = bh & 63;
    __shared__ float tile[512][65];
    __shared__ float st[512];
    const int tid = threadIdx.x;
    st[tid] = styles[b * 512 + tid];
    __syncthreads();
    const float* src = x + ((size_t)b * 512) * 4096 + h * 64;
#pragma unroll
    for (int it = 0; it < 16; ++it) {
        int idx = it * 512 + tid;               // 0..8191
        int c = idx >> 4, w4 = (idx & 15) * 4;
        float4 v = *(const float4*)(src + (size_t)c * 4096 + w4);
        float s = st[c];
        tile[c][w4] = v.x * s; tile[c][w4 + 1] = v.y * s;
        tile[c][w4 + 2] = v.z * s; tile[c][w4 + 3] = v.w * s;
    }
    __syncthreads();
    const int w = tid >> 3, l3 = tid & 7;
    unsigned short* outp = xt + (((size_t)bh * 64 + w) << 9) + l3 * 64;
#pragma unroll
    for (int g = 0; g < 8; ++g) {
        int bb = (g ^ l3) * 8;                  // XOR block order: 2-way banks (free)
        int c0 = l3 * 64 + bb;
        unsigned pk0 = (unsigned)f2bf(tile[c0 + 0][w]) | ((unsigned)f2bf(tile[c0 + 1][w]) << 16);
        unsigned pk1 = (unsigned)f2bf(tile[c0 + 2][w]) | ((unsigned)f2bf(tile[c0 + 3][w]) << 16);
        unsigned pk2 = (unsigned)f2bf(tile[c0 + 4][w]) | ((unsigned)f2bf(tile[c0 + 5][w]) << 16);
        unsigned pk3 = (unsigned)f2bf(tile[c0 + 6][w]) | ((unsigned)f2bf(tile[c0 + 7][w]) << 16);
        *(uint4*)(outp + bb) = make_uint4(pk0, pk1, pk2, pk3);
    }
}

// ---------------- main conv: implicit GEMM, 256x256 tile ----
// 8 waves (2M x 4N), BK=64, linear LDS tiles (256 rows x 64 halfs, XOR-quad swizzle).
// LDS-port-bound regime: per K-tile per CU, LDS ~2800 cyc vs MFMA ~2065 cyc. The
// fix over r2: no sched_barrier(0) walls; sched_group_barrier interleaves
// {1 ds_read : 2-4 MFMA} so each wave feeds the LDS unit DURING its MFMA stream.
// Barrier structure (proven r1/r2): per K-tile only
//   B2 = {lgkmcnt(0); barrier} before staging  (WAR: all reads of buf[cur] done)
//   B1 = {vmcnt(8);   barrier} after staging   (buf[nxt] fully landed; counted, not 0)
__global__ __launch_bounds__(512, 2)
void k_conv(const unsigned short* __restrict__ wA, const unsigned short* __restrict__ xt,
            const float* __restrict__ dcoefs,
            const float* __restrict__ noise, const float* __restrict__ nstr,
            const float* __restrict__ bias, float* __restrict__ out) {
    __shared__ __align__(16) unsigned short lA[2][16384];   // [dbuf][256 rows * 64 halfs]
    __shared__ __align__(16) unsigned short lB[2][16384];
    __shared__ float sdc[256];
    __shared__ float sbias[256];

    const int tid  = threadIdx.x;
    const int lane = tid & 63;
    const int wave = tid >> 6;
    const int wm = wave >> 2;      // 0..1  (M waves: 128 o-rows each)
    const int wn = wave & 3;       // 0..3  (N waves: 64 pixels each)

    const int orig  = blockIdx.x;
    const int wgid  = (orig & 7) * 64 + (orig >> 3);   // XCD-aware bijective swizzle
    const int o_blk = wgid & 1;
    const int ptile = wgid >> 1;           // 0..255
    const int b     = ptile >> 4;          // batch
    const int h0    = (ptile & 15) << 2;   // 4 image rows per 256-pixel tile
    const int o0    = o_blk * 256;
    const int p0    = (ptile & 15) << 8;   // pixel base

    const int srow  = tid >> 3;                        // staged row 0..63
    const int qsrc8 = ((tid & 7) ^ (srow & 7)) * 8;    // inverse-swizzled source quad (halfs)

    const int l7 = lane & 7;
    const int a_off = (wm * 128 + (lane & 15)) * 128;
    const int b_off = (wn * 64  + (lane & 15)) * 128;
    const int qk0 = (((lane >> 4)    ) ^ l7) * 16;     // ks=0 phys quad (bytes)
    const int qk1 = (((lane >> 4) | 4) ^ l7) * 16;     // ks=1 phys quad (bytes)

    // ---- incremental stage-pointer streams (recomputed once per tap) ----
    const unsigned short* pA;
    const unsigned short* pB[4];
    int aB[4];

    auto recompA = [&](int ktt) {
        pA = wA + (((size_t)((ktt >> 3) * COUT + o0 + srow)) << 9)
                + ((ktt & 7) << 6) + qsrc8;
    };
    auto recompB = [&](int ktt) {
        int tap = ktt >> 3;
        int ty = tap / 3;
        int dy = ty - 1, dx = tap - ty * 3 - 1;
        int wv = srow + dx;
        bool wok = (unsigned)wv < 64u;
        int i0 = (ktt & 7) << 6;
#pragma unroll
        for (int s = 0; s < 4; ++s) {
            int hh = h0 + s + dy;
            bool ok = wok && ((unsigned)hh < 64u);
            pB[s] = ok ? xt + (((size_t)(b * 4096 + hh * 64 + wv)) << 9) + i0 + qsrc8
                       : g_zero + qsrc8;
            aB[s] = ok ? 64 : 0;
        }
    };
    auto stageA = [&](int d) {
        char* lb = (char*)&lA[d][0] + wave * 1024;
        gload16(pA,               lb);
        gload16(pA + (64  << 9),  lb + 8192);
        gload16(pA + (128 << 9),  lb + 16384);
        gload16(pA + (192 << 9),  lb + 24576);
    };
    auto stageB = [&](int d) {
        char* lb = (char*)&lB[d][0] + wave * 1024;
        gload16(pB[0], lb);
        gload16(pB[1], lb + 8192);
        gload16(pB[2], lb + 16384);
        gload16(pB[3], lb + 24576);
    };

    bf16x8 afr[2][4], bfr[2][4];
    f32x4 acc[8][4];
#pragma unroll
    for (int i = 0; i < 8; ++i)
#pragma unroll
        for (int j = 0; j < 4; ++j) acc[i][j] = (f32x4){0.f, 0.f, 0.f, 0.f};

#define RD_A(S, H, QK, BASE) do {                                            \
    afr[S][0] = *(const bf16x8*)((BASE) + a_off + ((H)*4 + 0)*2048 + (QK));  \
    afr[S][1] = *(const bf16x8*)((BASE) + a_off + ((H)*4 + 1)*2048 + (QK));  \
    afr[S][2] = *(const bf16x8*)((BASE) + a_off + ((H)*4 + 2)*2048 + (QK));  \
    afr[S][3] = *(const bf16x8*)((BASE) + a_off + ((H)*4 + 3)*2048 + (QK));  \
} while (0)
#define RD_B(S, QK, BASE) do {                                               \
    bfr[S][0] = *(const bf16x8*)((BASE) + b_off + 0*2048 + (QK));            \
    bfr[S][1] = *(const bf16x8*)((BASE) + b_off + 1*2048 + (QK));            \
    bfr[S][2] = *(const bf16x8*)((BASE) + b_off + 2*2048 + (QK));            \
    bfr[S][3] = *(const bf16x8*)((BASE) + b_off + 3*2048 + (QK));            \
} while (0)
#define MM(AS, BS, H) do {                                                   \
    _Pragma("unroll")                                                        \
    for (int _j = 0; _j < 4; ++_j) {                                         \
        _Pragma("unroll")                                                    \
        for (int _fn = 0; _fn < 4; ++_fn)                                    \
            acc[(H)*4 + _j][_fn] = __builtin_amdgcn_mfma_f32_16x16x32_bf16(  \
                afr[AS][_j], bfr[BS][_fn], acc[(H)*4 + _j][_fn], 0, 0, 0);   \
    }                                                                        \
} while (0)
// sched_group_barrier masks: DS_READ=0x100, MFMA=0x8.
#define SGB_R1M4 do { _Pragma("unroll")                                      \
    for (int _u = 0; _u < 4; ++_u) {                                         \
        __builtin_amdgcn_sched_group_barrier(0x100, 1, 0);                   \
        __builtin_amdgcn_sched_group_barrier(0x008, 4, 0);                   \
    } } while (0)
#define SGB_R1M2 do { _Pragma("unroll")                                      \
    for (int _u = 0; _u < 8; ++_u) {                                         \
        __builtin_amdgcn_sched_group_barrier(0x100, 1, 0);                   \
        __builtin_amdgcn_sched_group_barrier(0x008, 2, 0);                   \
    } } while (0)

    // ---- prologue: stage tiles 0 and 1; counted landing; initial ks0 reads ----
    recompA(0); recompB(0); stageA(0); stageB(0);
    recompA(1); recompB(1); stageA(1); stageB(1);
    recompA(2); recompB(2);                       // stream state for kt=0 staging (ktt=2)
    asm volatile("s_waitcnt vmcnt(8)" ::: "memory");   // tile0 landed, tile1 in flight
    __builtin_amdgcn_s_barrier();
    {
        const char* bA0 = (const char*)&lA[0][0];
        const char* bB0 = (const char*)&lB[0][0];
        RD_A(0, 0, qk0, bA0);
        RD_B(0, qk0, bB0);
    }

    // ---- main loop: kt = 0..69 (always stages kt+2, always has next-tile reads) ----
    for (int kt = 0; kt < K_TILES - 2; ++kt) {
        const int cur = kt & 1;
        const char* bA = (const char*)&lA[cur][0];
        const char* bB = (const char*)&lB[cur][0];
        const char* nA = (const char*)&lA[cur ^ 1][0];
        const char* nB = (const char*)&lB[cur ^ 1][0];

        // ph0: A(h1,ks0) reads interleaved into MFMA h0 x ks0
        __builtin_amdgcn_s_setprio(1);
        RD_A(1, 1, qk0, bA);
        MM(0, 0, 0);
        SGB_R1M4;
        __builtin_amdgcn_s_setprio(0);

        // ph1: A(h0,ks1) + B(ks1) reads interleaved into MFMA h1 x ks0
        __builtin_amdgcn_s_setprio(1);
        RD_A(0, 0, qk1, bA);
        RD_B(1, qk1, bB);
        MM(1, 0, 1);
        SGB_R1M2;
        __builtin_amdgcn_s_setprio(0);

        // ph2: A(h1,ks1) reads interleaved into MFMA h0 x ks1
        __builtin_amdgcn_s_setprio(1);
        RD_A(1, 1, qk1, bA);
        MM(0, 1, 0);
        SGB_R1M4;
        __builtin_amdgcn_s_setprio(0);

        asm volatile("s_waitcnt lgkmcnt(0)" ::: "memory");
        __builtin_amdgcn_s_barrier();                         // B2: cur reads all done

        stageA(cur); stageB(cur);                             // stage kt+2 into buf[cur]
        {
            int nk = kt + 3;
            if (nk < K_TILES) {
                if ((nk & 7) == 0) { recompA(nk); recompB(nk); }
                else {
                    pA += 64;
                    pB[0] += aB[0]; pB[1] += aB[1]; pB[2] += aB[2]; pB[3] += aB[3];
                }
            }
        }
        asm volatile("s_waitcnt vmcnt(8)" ::: "memory");      // kt+1 fully landed
        __builtin_amdgcn_s_barrier();                         // B1

        // ph3: next-tile ks0 reads interleaved into MFMA h1 x ks1
        __builtin_amdgcn_s_setprio(1);
        RD_A(0, 0, qk0, nA);
        RD_B(0, qk0, nB);
        MM(1, 1, 1);
        SGB_R1M2;
        __builtin_amdgcn_s_setprio(0);
    }

    // ---- peeled kt = 70 (no staging; drain tile 71) ----
    {
        const char* bA = (const char*)&lA[0][0];
        const char* bB = (const char*)&lB[0][0];
        const char* nA = (const char*)&lA[1][0];
        const char* nB = (const char*)&lB[1][0];
        RD_A(1, 1, qk0, bA); MM(0, 0, 0);
        RD_A(0, 0, qk1, bA); RD_B(1, qk1, bB); MM(1, 0, 1);
        RD_A(1, 1, qk1, bA); MM(0, 1, 0);
        asm volatile("s_waitcnt vmcnt(0)" ::: "memory");      // tile 71 landed (own loads)
        __builtin_amdgcn_s_barrier();                         // block-wide
        RD_A(0, 0, qk0, nA); RD_B(0, qk0, nB); MM(1, 1, 1);
    }
    // ---- peeled kt = 71 (last tile, buf 1) ----
    {
        const char* bA = (const char*)&lA[1][0];
        const char* bB = (const char*)&lB[1][0];
        RD_A(1, 1, qk0, bA); MM(0, 0, 0);
        RD_A(0, 0, qk1, bA); RD_B(1, qk1, bB); MM(1, 0, 1);
        RD_A(1, 1, qk1, bA); MM(0, 1, 0);
        MM(1, 1, 1);
    }

    // ---- epilogue ----
    if (tid < 256) {
        sdc[tid]   = dcoefs[b * 512 + o0 + tid];
        sbias[tid] = bias[o0 + tid];
    }
    __syncthreads();
    const float ns = nstr[0];
    const int prow = (lane >> 4) * 4;
#pragma unroll
    for (int fm = 0; fm < 8; ++fm) {
        const int ob = wm * 128 + fm * 16 + prow;     // o - o0
#pragma unroll
        for (int fn = 0; fn < 4; ++fn) {
            const int p = p0 + wn * 64 + fn * 16 + (lane & 15);
            const float nv = noise[p] * ns;
#pragma unroll
            for (int rg = 0; rg < 4; ++rg) {
                const int oo = ob + rg;
                float v = acc[fm][fn][rg] * sdc[oo] + nv + sbias[oo];
                v = (v > 0.f ? v : 0.2f * v) * 1.41421356f;
                out[((size_t)(b * COUT + o0 + oo) << 12) + p] = v;
            }
        }
    }
#undef RD_A
#undef RD_B
#undef MM
#undef SGB_R1M4
#undef SGB_R1M2
}

// -------- fallback: fully self-contained fp32 conv (touches NO workspace) --------
__global__ void k_conv_naive(const float* __restrict__ x, const float* __restrict__ w,
                             const float* __restrict__ weight,
                             const float* __restrict__ aw, const float* __restrict__ ab,
                             const float* __restrict__ noise, const float* __restrict__ nstr,
                             const float* __restrict__ bias, float* __restrict__ out) {
    const int o = blockIdx.x, b = blockIdx.y;
    __shared__ float ss[512];
    __shared__ float red[256];
    const float* wv = w + b * 512;
    for (int i = threadIdx.x; i < 512; i += 256) {
        const float* arow = aw + (size_t)i * 512;
        float acc = 0.f;
        for (int k = 0; k < 512; ++k) acc += wv[k] * arow[k];
        ss[i] = acc * 0.04419417382415922f + ab[i];
    }
    __syncthreads();
    float part = 0.f;
    for (int i = threadIdx.x; i < 512; i += 256) {
        float s = ss[i], sq = 0.f;
#pragma unroll
        for (int k = 0; k < 9; ++k) { float v = weight[((size_t)o * 512 + i) * 9 + k]; sq += v * v; }
        part += s * s * sq;
    }
    red[threadIdx.x] = part;
    __syncthreads();
    for (int st = 128; st; st >>= 1) {
        if (threadIdx.x < st) red[threadIdx.x] += red[threadIdx.x + st];
        __syncthreads();
    }
    const float dcoef = rsqrtf(red[0] + 1e-8f);

    float acc[16];
#pragma unroll
    for (int j = 0; j < 16; ++j) acc[j] = 0.f;
    for (int i = 0; i < 512; ++i) {
        const float s = ss[i];
        float wk[9];
#pragma unroll
        for (int k = 0; k < 9; ++k) wk[k] = weight[((size_t)o * 512 + i) * 9 + k] * s;
        const float* xp = x + ((size_t)b * 512 + i) * 4096;
#pragma unroll
        for (int j = 0; j < 16; ++j) {
            const int p = (j << 8) + threadIdx.x;
            const int h = p >> 6, ww = p & 63;
            float a = acc[j];
#pragma unroll
            for (int ky = 0; ky < 3; ++ky) {
                int hh = h + ky - 1;
                if ((unsigned)hh < 64u) {
#pragma unroll
                    for (int kx = 0; kx < 3; ++kx) {
                        int wv2 = ww + kx - 1;
                        if ((unsigned)wv2 < 64u) a += wk[ky * 3 + kx] * xp[hh * 64 + wv2];
                    }
                }
            }
            acc[j] = a;
        }
    }
    const float ns = nstr[0], bs = bias[o];
#pragma unroll
    for (int j = 0; j < 16; ++j) {
        int p = (j << 8) + threadIdx.x;
        float v = acc[j] * dcoef + noise[p] * ns + bs;
        v = (v > 0.f ? v : 0.2f * v) * 1.41421356f;
        out[((size_t)(b * COUT + o) << 12) + p] = v;
    }
}

extern "C" void kernel_launch(void* const* d_in, const int* in_sizes, int n_in,
                              void* d_out, int out_size, void* d_ws, size_t ws_size,
                              hipStream_t stream) {
    const float* x   = (const float*)d_in[0];
    const float* w   = (const float*)d_in[1];
    const float* wt  = (const float*)d_in[2];
    const float* aw  = (const float*)d_in[3];
    const float* ab  = (const float*)d_in[4];
    const float* bs  = (const float*)d_in[5];
    const float* nc  = (const float*)d_in[6];
    const float* nst = (const float*)d_in[7];
    float* out = (float*)d_out;

    char* ws = (char*)d_ws;
    float* styles = (float*)ws;                                  // 32 KB
    float* dcoefs = (float*)(ws + 32 * 1024);                    // 32 KB
    float* wsq    = (float*)(ws + 64 * 1024);                    // 1 MB
    unsigned short* wA = (unsigned short*)(ws + (2 << 20));      // 4.7 MB
    unsigned short* xt = (unsigned short*)(ws + (2 << 20) + 4718592ull); // 67.1 MB
    const size_t need = (size_t)(2 << 20) + 4718592ull + 67108864ull;    // ~70.5 MB

    if (d_ws != nullptr && ws_size >= need) {
        k_prep1<<<2560, 256, 0, stream>>>(w, aw, ab, wt, styles, wA, wsq);
        k_dcoefs<<<2048, 256, 0, stream>>>(wsq, styles, dcoefs);
        k_xpose<<<1024, 512, 0, stream>>>(x, styles, xt);
        k_conv<<<512, 512, 0, stream>>>(wA, xt, dcoefs, nc, nst, bs, out);
    } else {
        k_conv_naive<<<dim3(512, 16), 256, 0, stream>>>(x, w, wt, aw, ab, nc, nst, bs, out);
    }
}